// Round 11
// baseline (172.527 us; speedup 1.0000x reference)
//
#include <hip/hip_runtime.h>
#include <cmath>

#define BATCH 32768
#define DIM   128
#define HID   512
#define NPAD  2048     // 64 transformed dims * 32 (29 coeffs padded to 32)

typedef __attribute__((ext_vector_type(8))) _Float16 half8;
typedef __attribute__((ext_vector_type(8))) short   short8v;
typedef __attribute__((ext_vector_type(4))) float   f32x4;
typedef unsigned short u16;

// ---------------------------------------------------------------------------
// Fragment-linear (FL) layout for a [R][K] f16 operand (R%16==0, K%32==0):
//   off(r,k) = ((kt*(R/16) + (r>>4))*64 + ((r&15) | (((k&31)>>3)<<4)))*8 + (k&7)
// MFMA lane l's 8 elements are the contiguous 16B at lane offset l*16.
// v11: BARRIER-FREE mainloop. Both A and B fragments are contiguous per-wave
// 1KB bursts in FL global layout -> load straight global->VGPR, double
// buffered (distance 1). No LDS, no barriers, no vmcnt asm in the mainloop;
// waves run independently; compiler schedules waits. A is fetched 2x from L2
// (2 waves share rows) - well under the 34.5 TB/s L2 ceiling.
// ---------------------------------------------------------------------------

__device__ __forceinline__ u16 f2h(float f) {
  _Float16 h = (_Float16)f;
  union { _Float16 h; u16 u; } v; v.h = h; return v.u;
}

// T1: bijective XCD-aware block swizzle (requires nwg % 8 == 0)
__device__ __forceinline__ int xcd_swz(int bid, int nwg) {
  int cpx = nwg >> 3;
  return (bid & 7) * cpx + (bid >> 3);
}

// ---------------- merged prep kernel (produce FL f16 operands) ----------------

__global__ __launch_bounds__(256) void prep_all_v11(
    const float* __restrict__ z, const float* __restrict__ W1, const float* __restrict__ W2,
    const float* __restrict__ W3, const float* __restrict__ b3,
    u16* __restrict__ zh, u16* __restrict__ W1h, u16* __restrict__ W2h,
    u16* __restrict__ W3h, float* __restrict__ b3p) {
  const int bid = blockIdx.x;
  if (bid < 1024) {                                // za: 2*2048*64 lane-frags
    int id = bid * 256 + threadIdx.x;
    int l = id & 63, mb = (id >> 6) & 2047, kt = id >> 17;
    int r = mb * 16 + (l & 15);
    int k0 = kt * 32 + ((l >> 4) << 3);            // < 64: masked first half only
    const float* src = z + (size_t)r * DIM + k0;
    short8v H;
#pragma unroll
    for (int j = 0; j < 8; ++j) H[j] = (short)f2h(src[j]);
    *(short8v*)(zh + (size_t)id * 8) = H;
  } else if (bid < 1168) {                         // W1 (4096) + W2 (32768) frags
    int id = (bid - 1024) * 256 + threadIdx.x;
    if (id < 4096) {                               // W1: R=512, K=64 (first 64 cols)
      int l = id & 63, mb = (id >> 6) & 31, kt = id >> 11;
      int r = mb * 16 + (l & 15);
      int k0 = kt * 32 + ((l >> 4) << 3);
      const float* src = W1 + (size_t)r * DIM + k0;
      short8v H;
#pragma unroll
      for (int j = 0; j < 8; ++j) H[j] = (short)f2h(src[j]);
      *(short8v*)(W1h + (size_t)id * 8) = H;
    } else {                                       // W2: R=512, K=512
      int id2 = id - 4096;
      int l = id2 & 63, mb = (id2 >> 6) & 31, kt = id2 >> 11;
      int r = mb * 16 + (l & 15);
      int k0 = kt * 32 + ((l >> 4) << 3);
      const float* src = W2 + (size_t)r * HID + k0;
      short8v H;
#pragma unroll
      for (int j = 0; j < 8; ++j) H[j] = (short)f2h(src[j]);
      *(short8v*)(W2h + (size_t)id2 * 8) = H;
    }
  } else if (bid < 1680) {                         // W3: R=2048, K=512
    int id = (bid - 1168) * 256 + threadIdx.x;
    int l = id & 63, mb = (id >> 6) & 127, kt = id >> 13;
    int n = mb * 16 + (l & 15);
    int k0 = kt * 32 + ((l >> 4) << 3);
    int g = n >> 5, kk = n & 31;
    short8v H;
    if (kk < 29) {
      const float* src = W3 + ((size_t)((g + 64) * 29 + kk)) * HID + k0;
#pragma unroll
      for (int j = 0; j < 8; ++j) H[j] = (short)f2h(src[j]);
    } else {
#pragma unroll
      for (int j = 0; j < 8; ++j) H[j] = 0;
    }
    *(short8v*)(W3h + (size_t)id * 8) = H;
  } else {                                         // b3p: 2048
    int n = (bid - 1680) * 256 + threadIdx.x;
    int g = n >> 5, kk = n & 31;
    b3p[n] = (kk < 29) ? b3[(g + 64) * 29 + kk] : 0.f;
  }
}

// ------------- v11 barrier-free mainloop: BM=BN=128, BK=32, 4 waves (2x2) -------------

template<int NKT>
__device__ __forceinline__ void gemm_mainloop_v11(
    const u16* __restrict__ A, const u16* __restrict__ B,
    int a_mb0, int a_rs16, int b_nb0, int b_rs16, f32x4 acc[4][4]) {
  const int lane = threadIdx.x & 63;
  const int wv = threadIdx.x >> 6;
  const int wr = wv >> 1, wc = wv & 1;
  const size_t aStep = (size_t)a_rs16 * 512;       // u16 per K-tile
  const size_t bStep = (size_t)b_rs16 * 512;
  const u16* Ap = A + (((size_t)(a_mb0 + wr * 4)) * 64 + lane) * 8;
  const u16* Bp = B + (((size_t)(b_nb0 + wc * 4)) * 64 + lane) * 8;

  half8 a[2][4], b[2][4];
#pragma unroll
  for (int f = 0; f < 4; ++f) {
    a[0][f] = *(const half8*)(Ap + f * 512);
    b[0][f] = *(const half8*)(Bp + f * 512);
  }
#pragma unroll
  for (int kt = 0; kt < NKT; ++kt) {
    const int cur = kt & 1, nxt = cur ^ 1;
    if (kt + 1 < NKT) {
#pragma unroll
      for (int f = 0; f < 4; ++f) {
        a[nxt][f] = *(const half8*)(Ap + (size_t)(kt + 1) * aStep + f * 512);
        b[nxt][f] = *(const half8*)(Bp + (size_t)(kt + 1) * bStep + f * 512);
      }
    }
#pragma unroll
    for (int mf = 0; mf < 4; ++mf)
#pragma unroll
      for (int nf = 0; nf < 4; ++nf)
        acc[mf][nf] = __builtin_amdgcn_mfma_f32_16x16x32_f16(a[cur][mf], b[cur][nf], acc[mf][nf], 0, 0, 0);
  }
}

// ---------------- GEMM + bias + relu -> f16 (FL output, R=BATCH) ----------------

template<int NKT>
__global__ __launch_bounds__(256, 3) void gemm_relu_v11(
    const u16* __restrict__ A, const u16* __restrict__ B,
    const float* __restrict__ bias, u16* __restrict__ C, int a_rs16) {
  const int bid = xcd_swz(blockIdx.x, gridDim.x);
  const int nt = bid & 3;                         // N = 512
  const int mt = bid >> 2;
  const int m0 = mt << 7, n0 = nt << 7;
  f32x4 zero = {0.f, 0.f, 0.f, 0.f};
  f32x4 acc[4][4];
#pragma unroll
  for (int i = 0; i < 4; ++i)
#pragma unroll
    for (int j = 0; j < 4; ++j) acc[i][j] = zero;

  gemm_mainloop_v11<NKT>(A, B, m0 >> 4, a_rs16, n0 >> 4, 32, acc);

  const int lane = threadIdx.x & 63;
  const int wv = threadIdx.x >> 6;
  const int wr = wv >> 1, wc = wv & 1;
#pragma unroll
  for (int mf = 0; mf < 4; ++mf) {
#pragma unroll
    for (int nf = 0; nf < 4; ++nf) {
      int col = n0 + wc * 64 + nf * 16 + (lane & 15);
      float bv = bias[col];
#pragma unroll
      for (int r = 0; r < 4; ++r) {
        int row = m0 + wr * 64 + mf * 16 + (lane >> 4) * 4 + r;
        float v = fmaxf(acc[mf][nf][r] + bv, 0.f);
        // FL store (R=BATCH, rs16=2048)
        int ktO = col >> 5, mbO = row >> 4;
        int lO = (row & 15) | (((col >> 3) & 3) << 4);
        int jO = col & 7;
        size_t off = (((size_t)ktO * (BATCH >> 4) + mbO) * 64 + lO) * 8 + jO;
        C[off] = f2h(v);
      }
    }
  }
}

// ---------------- RQS spline (per (row, dim)) ----------------

__device__ __forceinline__ void rqs(float xin, const float uw[10], const float uh[10], const float ud9[9],
                                    float& yv, float& ldv) {
  float mw = uw[0];
#pragma unroll
  for (int i = 1; i < 10; ++i) mw = fmaxf(mw, uw[i]);
  float ew[10]; float sw = 0.f;
#pragma unroll
  for (int i = 0; i < 10; ++i) { ew[i] = __expf(uw[i] - mw); sw += ew[i]; }
  float invw = 0.99f / sw;
  float cw[11]; cw[0] = -5.f;
  {
    float run = 0.f;
#pragma unroll
    for (int i = 0; i < 10; ++i) { run += 0.001f + invw * ew[i]; cw[i + 1] = 10.f * run - 5.f; }
  }
  cw[10] = 5.f;
  float mh = uh[0];
#pragma unroll
  for (int i = 1; i < 10; ++i) mh = fmaxf(mh, uh[i]);
  float eh[10]; float sh = 0.f;
#pragma unroll
  for (int i = 0; i < 10; ++i) { eh[i] = __expf(uh[i] - mh); sh += eh[i]; }
  float invh = 0.99f / sh;
  float ch[11]; ch[0] = -5.f;
  {
    float run = 0.f;
#pragma unroll
    for (int i = 0; i < 10; ++i) { run += 0.001f + invh * eh[i]; ch[i + 1] = 10.f * run - 5.f; }
  }
  ch[10] = 5.f;
  float dv[11]; dv[0] = 1.f; dv[10] = 1.f;
#pragma unroll
  for (int i = 0; i < 9; ++i) {
    float x = ud9[i];
    float sp = fmaxf(x, 0.f) + __logf(1.f + __expf(-fabsf(x)));
    dv[i + 1] = 0.001f + sp;
  }

  float xc = fminf(fmaxf(xin, -5.f), 5.f);
  int b = 0;
#pragma unroll
  for (int j = 1; j <= 10; ++j) b += (cw[j] <= xc) ? 1 : 0;
  b = (b > 9) ? 9 : b;

  float wk = cw[1] - cw[0], cwk = cw[0], hk = ch[1] - ch[0], chk = ch[0], dk = dv[0], dk1 = dv[1];
#pragma unroll
  for (int j = 1; j < 10; ++j) {
    if (j == b) { wk = cw[j + 1] - cw[j]; cwk = cw[j]; hk = ch[j + 1] - ch[j]; chk = ch[j]; dk = dv[j]; dk1 = dv[j + 1]; }
  }

  float th = (xc - cwk) / wk;
  float sr = hk / wk;
  float omth = 1.f - th;
  float tm = th * omth;
  float den = sr + (dk + dk1 - 2.f * sr) * tm;
  float num = hk * (sr * th * th + dk * tm);
  float y = chk + num / den;
  float ld = __logf(sr * sr * (dk1 * th * th + 2.f * sr * tm + dk * omth * omth)) - 2.f * __logf(den);
  bool inside = (xin >= -5.f) && (xin <= 5.f);
  yv = inside ? y : xin;
  ldv = inside ? ld : 0.f;
  if (!isfinite(yv)) yv = 0.f;
}

// ---------------- GEMM3 fused with spline epilogue ----------------
// PT: row stride 132 f32 (== 4 mod 32), dim-group stride 33 => 2-way max (free).

__global__ __launch_bounds__(256, 3) void gemm3_spline_v11(
    const u16* __restrict__ A, const u16* __restrict__ B,
    const float* __restrict__ b3p, const float* __restrict__ z,
    float* __restrict__ xout, float* __restrict__ partial) {
  __shared__ __align__(16) float PTf[64 * 132];   // 33792 B, spline transpose only
  const int bid = xcd_swz(blockIdx.x, gridDim.x);
  const int nt = bid & 15;
  const int mt = bid >> 4;
  const int m0 = mt << 7, n0 = nt << 7;
  f32x4 zero = {0.f, 0.f, 0.f, 0.f};
  f32x4 acc[4][4];
#pragma unroll
  for (int i = 0; i < 4; ++i)
#pragma unroll
    for (int j = 0; j < 4; ++j) acc[i][j] = zero;

  gemm_mainloop_v11<16>(A, B, m0 >> 4, BATCH >> 4, n0 >> 4, NPAD >> 4, acc);

  const int t = threadIdx.x;
  const int lane = t & 63;
  const int wv = t >> 6;
  const int wr = wv >> 1, wc = wv & 1;
  const int gb = n0 >> 5;   // global transformed-dim base for this block (4 dims)

  for (int p = 0; p < 2; ++p) {
    __syncthreads();
    if (wr == p) {
#pragma unroll
      for (int mf = 0; mf < 4; ++mf)
#pragma unroll
        for (int nf = 0; nf < 4; ++nf)
#pragma unroll
          for (int r = 0; r < 4; ++r) {
            int cl = wc * 64 + nf * 16 + (lane & 15);         // local col 0..127
            int rowl = mf * 16 + (lane >> 4) * 4 + r;         // 0..63
            PTf[rowl * 132 + (cl >> 5) * 33 + (cl & 31)] = acc[mf][nf][r];
          }
    }
    __syncthreads();

    const int rl = t >> 2;          // 0..63
    const int g = t & 3;            // local dim 0..3
    const int row = p * 64 + rl;
    const int grow = m0 + row;
    const float* pr = PTf + rl * 132 + g * 33;
    const float* bb = b3p + n0 + g * 32;
    float uw[10], uh[10], ud9[9];
#pragma unroll
    for (int i = 0; i < 10; ++i) uw[i] = pr[i] + bb[i];
#pragma unroll
    for (int i = 0; i < 10; ++i) uh[i] = pr[10 + i] + bb[10 + i];
#pragma unroll
    for (int i = 0; i < 9; ++i) ud9[i] = pr[20 + i] + bb[20 + i];

    float xin = z[(long)grow * DIM + 64 + gb + g];
    float yv, ldv;
    rqs(xin, uw, uh, ud9, yv, ldv);

    xout[(long)grow * DIM + 64 + gb + g] = yv;

    float s = ldv;
    s += __shfl_down(s, 1);
    s += __shfl_down(s, 2);
    if (g == 0) partial[(long)nt * BATCH + grow] = s;
  }
}

// ---------------- pass-through copy + logdet reduce ----------------

__global__ __launch_bounds__(256) void copy_first_v11(const float* __restrict__ z, float* __restrict__ xout) {
  int id = blockIdx.x * 256 + threadIdx.x;        // < 32768*16
  int m = id >> 4, c4 = id & 15;
  const float4 v = *(const float4*)(z + (long)m * DIM + c4 * 4);
  *(float4*)(xout + (long)m * DIM + c4 * 4) = v;
}

__global__ __launch_bounds__(256) void reduce_ld_v11(const float* __restrict__ partial, float* __restrict__ ldout) {
  int row = blockIdx.x * 256 + threadIdx.x;
  float s = 0.f;
#pragma unroll
  for (int i = 0; i < 16; ++i) s += partial[(long)i * BATCH + row];
  if (!isfinite(s)) s = 0.f;
  ldout[row] = s;
}

// ---------------- launch ----------------

extern "C" void kernel_launch(void* const* d_in, const int* in_sizes, int n_in,
                              void* d_out, int out_size, void* d_ws, size_t ws_size,
                              hipStream_t stream) {
  const float* z  = (const float*)d_in[0];
  const float* W1 = (const float*)d_in[1];
  const float* b1 = (const float*)d_in[2];
  const float* W2 = (const float*)d_in[3];
  const float* b2 = (const float*)d_in[4];
  const float* W3 = (const float*)d_in[5];
  const float* b3 = (const float*)d_in[6];
  float* xout  = (float*)d_out;
  float* ldout = xout + (size_t)BATCH * DIM;

  char* ws = (char*)d_ws;
  u16* W1h = (u16*)ws;  ws += (size_t)512 * 64 * 2;
  u16* W2h = (u16*)ws;  ws += (size_t)512 * 512 * 2;
  u16* W3h = (u16*)ws;  ws += (size_t)NPAD * HID * 2;
  float* b3p = (float*)ws; ws += (size_t)NPAD * 4;
  // za and part alias (disjoint lifetimes: za consumed by gemm1; part written by gemm3)
  u16* zah  = (u16*)ws;
  float* part = (float*)ws; ws += (size_t)BATCH * 64 * 2;   // 4 MB (part needs 2 MB)
  u16* h1h = (u16*)ws;  ws += (size_t)BATCH * HID * 2;
  u16* h2h = (u16*)ws;  ws += (size_t)BATCH * HID * 2;

  prep_all_v11<<<1688, 256, 0, stream>>>(z, W1, W2, W3, b3, zah, W1h, W2h, W3h, b3p);

  // GEMM1: A = za (R=BATCH, rs16=2048), K=64 (NKT=2)
  gemm_relu_v11<2><<<(BATCH / 128) * 4, 256, 0, stream>>>(zah, W1h, b1, h1h, BATCH >> 4);
  // GEMM2: A = h1 (R=BATCH), K=512 (NKT=16)
  gemm_relu_v11<16><<<(BATCH / 128) * 4, 256, 0, stream>>>(h1h, W2h, b2, h2h, BATCH >> 4);
  // GEMM3 + spline
  gemm3_spline_v11<<<(BATCH / 128) * (NPAD / 128), 256, 0, stream>>>(h2h, W3h, b3p, z, xout, part);

  copy_first_v11<<<(BATCH * 16) / 256, 256, 0, stream>>>(z, xout);
  reduce_ld_v11<<<BATCH / 256, 256, 0, stream>>>(part, ldout);
}

// Round 13
// 163.315 us; speedup vs baseline: 1.0564x; 1.0564x over previous
//
#include <hip/hip_runtime.h>
#include <cmath>

#define BATCH 32768
#define DIM   128
#define HID   512
#define NPAD  2048     // 64 transformed dims * 32 (29 coeffs padded to 32)

typedef __attribute__((ext_vector_type(8))) _Float16 half8;
typedef __attribute__((ext_vector_type(8))) short   short8v;
typedef __attribute__((ext_vector_type(4))) float   f32x4;
typedef unsigned short u16;

// ---------------------------------------------------------------------------
// Fragment-linear (FL) layout for a [R][K] f16 operand (R%16==0, K%32==0):
//   off(r,k) = ((kt*(R/16) + (r>>4))*64 + ((r&15) | (((k&31)>>3)<<4)))*8 + (k&7)
// v13 = v12 (BM=128 BN=256, wave-tile 64x128, acc[4][8]; A via global_load_lds
// 4x8KB dist-2; B global->VGPR dist-1) with RACE-FIXED vmcnt: count ONLY the
// pinned A-DMA ops (2 per iteration, fenced by asm "memory") -> steady
// vmcnt(4), tail vmcnt(2), last vmcnt(0). Compiler-scheduled B register loads
// cannot break the guarantee (they only add conservatism if issued pre-wait;
// their own consumers are protected by register dependencies).
// v12 bug: counted B loads in vmcnt math; compiler moved them -> A-tile race.
// ---------------------------------------------------------------------------

__device__ __forceinline__ u16 f2h(float f) {
  _Float16 h = (_Float16)f;
  union { _Float16 h; u16 u; } v; v.h = h; return v.u;
}

__device__ __forceinline__ void async16(const void* g, void* l) {
  __builtin_amdgcn_global_load_lds(
      (const __attribute__((address_space(1))) void*)g,
      (__attribute__((address_space(3))) void*)l, 16, 0, 0);
}

__device__ __forceinline__ void vwait(int n) {   // compile-time after unroll
  switch (n) {
    case 0:  asm volatile("s_waitcnt vmcnt(0)" ::: "memory"); break;
    case 2:  asm volatile("s_waitcnt vmcnt(2)" ::: "memory"); break;
    default: asm volatile("s_waitcnt vmcnt(4)" ::: "memory"); break;
  }
}

// T1: bijective XCD-aware block swizzle (requires nwg % 8 == 0)
__device__ __forceinline__ int xcd_swz(int bid, int nwg) {
  int cpx = nwg >> 3;
  return (bid & 7) * cpx + (bid >> 3);
}

// ---------------- merged prep kernel (produce FL f16 operands) ----------------

__global__ __launch_bounds__(256) void prep_all_v13(
    const float* __restrict__ z, const float* __restrict__ W1, const float* __restrict__ W2,
    const float* __restrict__ W3, const float* __restrict__ b3,
    u16* __restrict__ zh, u16* __restrict__ W1h, u16* __restrict__ W2h,
    u16* __restrict__ W3h, float* __restrict__ b3p) {
  const int bid = blockIdx.x;
  if (bid < 1024) {                                // za: 2*2048*64 lane-frags
    int id = bid * 256 + threadIdx.x;
    int l = id & 63, mb = (id >> 6) & 2047, kt = id >> 17;
    int r = mb * 16 + (l & 15);
    int k0 = kt * 32 + ((l >> 4) << 3);            // < 64: masked first half only
    const float* src = z + (size_t)r * DIM + k0;
    short8v H;
#pragma unroll
    for (int j = 0; j < 8; ++j) H[j] = (short)f2h(src[j]);
    *(short8v*)(zh + (size_t)id * 8) = H;
  } else if (bid < 1168) {                         // W1 (4096) + W2 (32768) frags
    int id = (bid - 1024) * 256 + threadIdx.x;
    if (id < 4096) {                               // W1: R=512, K=64 (first 64 cols)
      int l = id & 63, mb = (id >> 6) & 31, kt = id >> 11;
      int r = mb * 16 + (l & 15);
      int k0 = kt * 32 + ((l >> 4) << 3);
      const float* src = W1 + (size_t)r * DIM + k0;
      short8v H;
#pragma unroll
      for (int j = 0; j < 8; ++j) H[j] = (short)f2h(src[j]);
      *(short8v*)(W1h + (size_t)id * 8) = H;
    } else {                                       // W2: R=512, K=512
      int id2 = id - 4096;
      int l = id2 & 63, mb = (id2 >> 6) & 31, kt = id2 >> 11;
      int r = mb * 16 + (l & 15);
      int k0 = kt * 32 + ((l >> 4) << 3);
      const float* src = W2 + (size_t)r * HID + k0;
      short8v H;
#pragma unroll
      for (int j = 0; j < 8; ++j) H[j] = (short)f2h(src[j]);
      *(short8v*)(W2h + (size_t)id2 * 8) = H;
    }
  } else if (bid < 1680) {                         // W3: R=2048, K=512
    int id = (bid - 1168) * 256 + threadIdx.x;
    int l = id & 63, mb = (id >> 6) & 127, kt = id >> 13;
    int n = mb * 16 + (l & 15);
    int k0 = kt * 32 + ((l >> 4) << 3);
    int g = n >> 5, kk = n & 31;
    short8v H;
    if (kk < 29) {
      const float* src = W3 + ((size_t)((g + 64) * 29 + kk)) * HID + k0;
#pragma unroll
      for (int j = 0; j < 8; ++j) H[j] = (short)f2h(src[j]);
    } else {
#pragma unroll
      for (int j = 0; j < 8; ++j) H[j] = 0;
    }
    *(short8v*)(W3h + (size_t)id * 8) = H;
  } else {                                         // b3p: 2048
    int n = (bid - 1680) * 256 + threadIdx.x;
    int g = n >> 5, kk = n & 31;
    b3p[n] = (kk < 29) ? b3[(g + 64) * 29 + kk] : 0.f;
  }
}

// ------------- v13 mainloop: BM=128, BN=256, BK=32, 4 waves, wave-tile 64x128 -------------

__device__ __forceinline__ void stageA_v13(const u16* __restrict__ A, size_t ab, u16* Lb, int t) {
  async16(A + ab + t * 8,         Lb + t * 8);
  async16(A + ab + (t + 256) * 8, Lb + (t + 256) * 8);
}

template<int NKT>
__device__ __forceinline__ void gemm_mainloop_v13(
    const u16* __restrict__ A, const u16* __restrict__ B,
    int a_mb0, int a_rs16, int b_nb0, int b_rs16,
    u16* LDS, f32x4 acc[4][8]) {
  const int t = threadIdx.x;
  const int lane = t & 63;
  const int wv = t >> 6;
  const int wr = wv >> 1, wc = wv & 1;             // wr: row-half, wc: col-half(128)
  const size_t aStep = (size_t)a_rs16 * 512;       // u16 per K-tile
  const size_t bStep = (size_t)b_rs16 * 512;
  const size_t ab0 = (size_t)a_mb0 * 512;
  const u16* Bp = B + (((size_t)(b_nb0 + wc * 8)) * 64 + lane) * 8;

  half8 b[2][8];
#pragma unroll
  for (int nf = 0; nf < 8; ++nf) b[0][nf] = *(const half8*)(Bp + nf * 512);
  stageA_v13(A, ab0, LDS, t);
  if (NKT > 1) stageA_v13(A, ab0 + aStep, LDS + 4096, t);

#pragma unroll
  for (int kt = 0; kt < NKT; ++kt) {
    if (kt + 1 < NKT) {
#pragma unroll
      for (int nf = 0; nf < 8; ++nf)
        b[(kt + 1) & 1][nf] = *(const half8*)(Bp + (size_t)(kt + 1) * bStep + nf * 512);
    }
    if (kt + 2 < NKT)
      stageA_v13(A, ab0 + (size_t)(kt + 2) * aStep, LDS + ((kt + 2) & 3) * 4096, t);
    // A-only counting (B loads float freely; only pinned DMAs counted):
    // outstanding A-DMAs after A(kt): A(kt+1):2 [if exists] + A(kt+2):2 [if exists]
    if (kt + 2 < NKT)      vwait(4);
    else if (kt + 1 < NKT) vwait(2);
    else                   vwait(0);
    __builtin_amdgcn_s_barrier();                  // all waves see A(kt) in LDS
    __builtin_amdgcn_sched_barrier(0);             // pin ds_reads after barrier
    half8 a[4];
#pragma unroll
    for (int mf = 0; mf < 4; ++mf)
      a[mf] = *(const half8*)(LDS + (kt & 3) * 4096 + ((wr * 4 + mf) * 64 + lane) * 8);
#pragma unroll
    for (int mf = 0; mf < 4; ++mf)
#pragma unroll
      for (int nf = 0; nf < 8; ++nf)
        acc[mf][nf] = __builtin_amdgcn_mfma_f32_16x16x32_f16(a[mf], b[kt & 1][nf], acc[mf][nf], 0, 0, 0);
  }
}

// ---------------- GEMM + bias + relu -> f16 (FL output, R=BATCH) ----------------

template<int NKT, int NTL>
__global__ __launch_bounds__(256, 2) void gemm_relu_v13(
    const u16* __restrict__ A, const u16* __restrict__ B,
    const float* __restrict__ bias, u16* __restrict__ C, int a_rs16) {
  __shared__ __align__(16) u16 LDS[16384];        // 32 KB: 4 x 8 KB A-buffers
  const int bid = xcd_swz(blockIdx.x, gridDim.x);
  const int nt = bid & ((1 << NTL) - 1);
  const int mt = bid >> NTL;
  const int m0 = mt << 7, n0 = nt << 8;           // BN = 256
  f32x4 zero = {0.f, 0.f, 0.f, 0.f};
  f32x4 acc[4][8];
#pragma unroll
  for (int i = 0; i < 4; ++i)
#pragma unroll
    for (int j = 0; j < 8; ++j) acc[i][j] = zero;

  gemm_mainloop_v13<NKT>(A, B, m0 >> 4, a_rs16, n0 >> 4, 32, LDS, acc);

  const int lane = threadIdx.x & 63;
  const int wv = threadIdx.x >> 6;
  const int wr = wv >> 1, wc = wv & 1;
#pragma unroll
  for (int mf = 0; mf < 4; ++mf) {
#pragma unroll
    for (int nf = 0; nf < 8; ++nf) {
      int col = n0 + wc * 128 + nf * 16 + (lane & 15);
      float bv = bias[col];
#pragma unroll
      for (int r = 0; r < 4; ++r) {
        int row = m0 + wr * 64 + mf * 16 + (lane >> 4) * 4 + r;
        float v = fmaxf(acc[mf][nf][r] + bv, 0.f);
        // FL store (R=BATCH, rs16=2048)
        int ktO = col >> 5, mbO = row >> 4;
        int lO = (row & 15) | (((col >> 3) & 3) << 4);
        int jO = col & 7;
        size_t off = (((size_t)ktO * (BATCH >> 4) + mbO) * 64 + lO) * 8 + jO;
        C[off] = f2h(v);
      }
    }
  }
}

// ---------------- RQS spline (per (row, dim)) ----------------

__device__ __forceinline__ void rqs(float xin, const float uw[10], const float uh[10], const float ud9[9],
                                    float& yv, float& ldv) {
  float mw = uw[0];
#pragma unroll
  for (int i = 1; i < 10; ++i) mw = fmaxf(mw, uw[i]);
  float ew[10]; float sw = 0.f;
#pragma unroll
  for (int i = 0; i < 10; ++i) { ew[i] = __expf(uw[i] - mw); sw += ew[i]; }
  float invw = 0.99f / sw;
  float cw[11]; cw[0] = -5.f;
  {
    float run = 0.f;
#pragma unroll
    for (int i = 0; i < 10; ++i) { run += 0.001f + invw * ew[i]; cw[i + 1] = 10.f * run - 5.f; }
  }
  cw[10] = 5.f;
  float mh = uh[0];
#pragma unroll
  for (int i = 1; i < 10; ++i) mh = fmaxf(mh, uh[i]);
  float eh[10]; float sh = 0.f;
#pragma unroll
  for (int i = 0; i < 10; ++i) { eh[i] = __expf(uh[i] - mh); sh += eh[i]; }
  float invh = 0.99f / sh;
  float ch[11]; ch[0] = -5.f;
  {
    float run = 0.f;
#pragma unroll
    for (int i = 0; i < 10; ++i) { run += 0.001f + invh * eh[i]; ch[i + 1] = 10.f * run - 5.f; }
  }
  ch[10] = 5.f;
  float dv[11]; dv[0] = 1.f; dv[10] = 1.f;
#pragma unroll
  for (int i = 0; i < 9; ++i) {
    float x = ud9[i];
    float sp = fmaxf(x, 0.f) + __logf(1.f + __expf(-fabsf(x)));
    dv[i + 1] = 0.001f + sp;
  }

  float xc = fminf(fmaxf(xin, -5.f), 5.f);
  int b = 0;
#pragma unroll
  for (int j = 1; j <= 10; ++j) b += (cw[j] <= xc) ? 1 : 0;
  b = (b > 9) ? 9 : b;

  float wk = cw[1] - cw[0], cwk = cw[0], hk = ch[1] - ch[0], chk = ch[0], dk = dv[0], dk1 = dv[1];
#pragma unroll
  for (int j = 1; j < 10; ++j) {
    if (j == b) { wk = cw[j + 1] - cw[j]; cwk = cw[j]; hk = ch[j + 1] - ch[j]; chk = ch[j]; dk = dv[j]; dk1 = dv[j + 1]; }
  }

  float th = (xc - cwk) / wk;
  float sr = hk / wk;
  float omth = 1.f - th;
  float tm = th * omth;
  float den = sr + (dk + dk1 - 2.f * sr) * tm;
  float num = hk * (sr * th * th + dk * tm);
  float y = chk + num / den;
  float ld = __logf(sr * sr * (dk1 * th * th + 2.f * sr * tm + dk * omth * omth)) - 2.f * __logf(den);
  bool inside = (xin >= -5.f) && (xin <= 5.f);
  yv = inside ? y : xin;
  ldv = inside ? ld : 0.f;
  if (!isfinite(yv)) yv = 0.f;
}

// ---------------- GEMM3 fused with spline epilogue (BN=256: 8 dim-groups) ----------------
// 4 stripes: s_r = row-half (64 rows), s_c = col-half (4 dim-groups).
// PT[64][132]: row stride 132 == 4 mod 32, group stride 33 => <=2-way (free).

__global__ __launch_bounds__(256, 2) void gemm3_spline_v13(
    const u16* __restrict__ A, const u16* __restrict__ B,
    const float* __restrict__ b3p, const float* __restrict__ z,
    float* __restrict__ xout, float* __restrict__ partial) {
  __shared__ __align__(16) char SMEM[33792];      // 4 x 8 KB A-staging, aliased with PT
  u16* LDS = (u16*)SMEM;
  float* PTf = (float*)SMEM;                      // [64][132]
  const int bid = xcd_swz(blockIdx.x, gridDim.x);
  const int nt = bid & 7;                         // N = 2048 -> 8 n-tiles of 256
  const int mt = bid >> 3;
  const int m0 = mt << 7, n0 = nt << 8;
  f32x4 zero = {0.f, 0.f, 0.f, 0.f};
  f32x4 acc[4][8];
#pragma unroll
  for (int i = 0; i < 4; ++i)
#pragma unroll
    for (int j = 0; j < 8; ++j) acc[i][j] = zero;

  gemm_mainloop_v13<16>(A, B, m0 >> 4, BATCH >> 4, n0 >> 4, NPAD >> 4, LDS, acc);

  const int t = threadIdx.x;
  const int lane = t & 63;
  const int wv = t >> 6;
  const int wr = wv >> 1, wc = wv & 1;

#pragma unroll
  for (int s = 0; s < 4; ++s) {
    const int s_r = s >> 1, s_c = s & 1;
    __syncthreads();
    if (wr == s_r && wc == s_c) {
#pragma unroll
      for (int mf = 0; mf < 4; ++mf)
#pragma unroll
        for (int nf = 0; nf < 8; ++nf)
#pragma unroll
          for (int r = 0; r < 4; ++r) {
            int cp = nf * 16 + (lane & 15);                   // 0..127 within col-half
            int rowl = mf * 16 + (lane >> 4) * 4 + r;         // 0..63
            PTf[rowl * 132 + (cp >> 5) * 33 + (cp & 31)] = acc[mf][nf][r];
          }
    }
    __syncthreads();

    const int row = t >> 2;         // 0..63
    const int g4 = t & 3;           // group within col-half
    const int grow = m0 + s_r * 64 + row;
    const int gdim = (n0 >> 5) + s_c * 4 + g4;    // global transformed-dim 0..63
    const float* pr = PTf + row * 132 + g4 * 33;
    const float* bb = b3p + n0 + s_c * 128 + g4 * 32;
    float uw[10], uh[10], ud9[9];
#pragma unroll
    for (int i = 0; i < 10; ++i) uw[i] = pr[i] + bb[i];
#pragma unroll
    for (int i = 0; i < 10; ++i) uh[i] = pr[10 + i] + bb[10 + i];
#pragma unroll
    for (int i = 0; i < 9; ++i) ud9[i] = pr[20 + i] + bb[20 + i];

    float xin = z[(long)grow * DIM + 64 + gdim];
    float yv, ldv;
    rqs(xin, uw, uh, ud9, yv, ldv);

    xout[(long)grow * DIM + 64 + gdim] = yv;

    float sld = ldv;
    sld += __shfl_down(sld, 1);
    sld += __shfl_down(sld, 2);
    if (g4 == 0)
      partial[(size_t)(nt * 2 + s_c) * BATCH + grow] = sld;
  }
}

// ---------------- pass-through copy + logdet reduce ----------------

__global__ __launch_bounds__(256) void copy_first_v13(const float* __restrict__ z, float* __restrict__ xout) {
  int id = blockIdx.x * 256 + threadIdx.x;        // < 32768*16
  int m = id >> 4, c4 = id & 15;
  const float4 v = *(const float4*)(z + (long)m * DIM + c4 * 4);
  *(float4*)(xout + (long)m * DIM + c4 * 4) = v;
}

__global__ __launch_bounds__(256) void reduce_ld_v13(const float* __restrict__ partial, float* __restrict__ ldout) {
  int row = blockIdx.x * 256 + threadIdx.x;
  float s = 0.f;
#pragma unroll
  for (int i = 0; i < 16; ++i) s += partial[(long)i * BATCH + row];
  if (!isfinite(s)) s = 0.f;
  ldout[row] = s;
}

// ---------------- launch ----------------

extern "C" void kernel_launch(void* const* d_in, const int* in_sizes, int n_in,
                              void* d_out, int out_size, void* d_ws, size_t ws_size,
                              hipStream_t stream) {
  const float* z  = (const float*)d_in[0];
  const float* W1 = (const float*)d_in[1];
  const float* b1 = (const float*)d_in[2];
  const float* W2 = (const float*)d_in[3];
  const float* b2 = (const float*)d_in[4];
  const float* W3 = (const float*)d_in[5];
  const float* b3 = (const float*)d_in[6];
  float* xout  = (float*)d_out;
  float* ldout = xout + (size_t)BATCH * DIM;

  char* ws = (char*)d_ws;
  u16* W1h = (u16*)ws;  ws += (size_t)512 * 64 * 2;
  u16* W2h = (u16*)ws;  ws += (size_t)512 * 512 * 2;
  u16* W3h = (u16*)ws;  ws += (size_t)NPAD * HID * 2;
  float* b3p = (float*)ws; ws += (size_t)NPAD * 4;
  // za and part alias (disjoint lifetimes: za consumed by gemm1; part written by gemm3)
  u16* zah  = (u16*)ws;
  float* part = (float*)ws; ws += (size_t)BATCH * 64 * 2;   // 4 MB (part needs 2 MB)
  u16* h1h = (u16*)ws;  ws += (size_t)BATCH * HID * 2;
  u16* h2h = (u16*)ws;  ws += (size_t)BATCH * HID * 2;

  prep_all_v13<<<1688, 256, 0, stream>>>(z, W1, W2, W3, b3, zah, W1h, W2h, W3h, b3p);

  // GEMM1: A = za (R=BATCH), K=64 (NKT=2), N=512 -> 2 n-tiles of 256
  gemm_relu_v13<2, 1><<<(BATCH / 128) * 2, 256, 0, stream>>>(zah, W1h, b1, h1h, BATCH >> 4);
  // GEMM2: A = h1 (R=BATCH), K=512 (NKT=16), N=512
  gemm_relu_v13<16, 1><<<(BATCH / 128) * 2, 256, 0, stream>>>(h1h, W2h, b2, h2h, BATCH >> 4);
  // GEMM3 + spline: N=2048 -> 8 n-tiles of 256
  gemm3_spline_v13<<<(BATCH / 128) * (NPAD / 256), 256, 0, stream>>>(h2h, W3h, b3p, z, xout, part);

  copy_first_v13<<<(BATCH * 16) / 256, 256, 0, stream>>>(z, xout);
  reduce_ld_v13<<<BATCH / 256, 256, 0, stream>>>(part, ldout);
}

// Round 14
// 153.308 us; speedup vs baseline: 1.1254x; 1.0653x over previous
//
#include <hip/hip_runtime.h>
#include <cmath>

#define BATCH 32768
#define DIM   128
#define HID   512
#define NPAD  2048     // 64 transformed dims * 32 (29 coeffs padded to 32)

typedef __attribute__((ext_vector_type(8))) _Float16 half8;
typedef __attribute__((ext_vector_type(8))) short   short8v;
typedef __attribute__((ext_vector_type(4))) float   f32x4;
typedef unsigned short u16;

// ---------------------------------------------------------------------------
// Fragment-linear (FL) layout for a [R][K] f16 operand (R%16==0, K%32==0):
//   off(r,k) = ((kt*(R/16) + (r>>4))*64 + ((r&15) | (((k&31)>>3)<<4)))*8 + (k&7)
// v14 = v8 geometry (BM=BN=128, 4 waves 2x2, wave-tile 64x64, B in regs
// dist-1, A via global_load_lds) with BK=64 PHASES: 2 K-tiles per
// barrier/vwait. 6 x 8KB A-buffers in mod-3 PAIR rotation:
//   phase p computes pair p%3; stages pair (p+1)%3.
//   Race-safe: lagging wave is at worst in compute(p-1) reading (p-1)%3;
//   current waves read p%3; stage target (p+1)%3 is distinct from both.
// vmcnt counts ONLY pinned A-DMAs (v13 rule): steady vwait(4), last vwait(0).
// Per barrier per wave: 8 ds_read_b128 + 32 MFMA (vs v8's 4 + 16).
// ---------------------------------------------------------------------------

__device__ __forceinline__ u16 f2h(float f) {
  _Float16 h = (_Float16)f;
  union { _Float16 h; u16 u; } v; v.h = h; return v.u;
}

__device__ __forceinline__ void async16(const void* g, void* l) {
  __builtin_amdgcn_global_load_lds(
      (const __attribute__((address_space(1))) void*)g,
      (__attribute__((address_space(3))) void*)l, 16, 0, 0);
}

__device__ __forceinline__ void vwait(int n) {   // compile-time after unroll
  switch (n) {
    case 0:  asm volatile("s_waitcnt vmcnt(0)" ::: "memory"); break;
    default: asm volatile("s_waitcnt vmcnt(4)" ::: "memory"); break;
  }
}

// T1: bijective XCD-aware block swizzle (requires nwg % 8 == 0)
__device__ __forceinline__ int xcd_swz(int bid, int nwg) {
  int cpx = nwg >> 3;
  return (bid & 7) * cpx + (bid >> 3);
}

// ---------------- merged prep kernel (produce FL f16 operands) ----------------

__global__ __launch_bounds__(256) void prep_all_v14(
    const float* __restrict__ z, const float* __restrict__ W1, const float* __restrict__ W2,
    const float* __restrict__ W3, const float* __restrict__ b3,
    u16* __restrict__ zh, u16* __restrict__ W1h, u16* __restrict__ W2h,
    u16* __restrict__ W3h, float* __restrict__ b3p) {
  const int bid = blockIdx.x;
  if (bid < 1024) {                                // za: 2*2048*64 lane-frags
    int id = bid * 256 + threadIdx.x;
    int l = id & 63, mb = (id >> 6) & 2047, kt = id >> 17;
    int r = mb * 16 + (l & 15);
    int k0 = kt * 32 + ((l >> 4) << 3);            // < 64: masked first half only
    const float* src = z + (size_t)r * DIM + k0;
    short8v H;
#pragma unroll
    for (int j = 0; j < 8; ++j) H[j] = (short)f2h(src[j]);
    *(short8v*)(zh + (size_t)id * 8) = H;
  } else if (bid < 1168) {                         // W1 (4096) + W2 (32768) frags
    int id = (bid - 1024) * 256 + threadIdx.x;
    if (id < 4096) {                               // W1: R=512, K=64 (first 64 cols)
      int l = id & 63, mb = (id >> 6) & 31, kt = id >> 11;
      int r = mb * 16 + (l & 15);
      int k0 = kt * 32 + ((l >> 4) << 3);
      const float* src = W1 + (size_t)r * DIM + k0;
      short8v H;
#pragma unroll
      for (int j = 0; j < 8; ++j) H[j] = (short)f2h(src[j]);
      *(short8v*)(W1h + (size_t)id * 8) = H;
    } else {                                       // W2: R=512, K=512
      int id2 = id - 4096;
      int l = id2 & 63, mb = (id2 >> 6) & 31, kt = id2 >> 11;
      int r = mb * 16 + (l & 15);
      int k0 = kt * 32 + ((l >> 4) << 3);
      const float* src = W2 + (size_t)r * HID + k0;
      short8v H;
#pragma unroll
      for (int j = 0; j < 8; ++j) H[j] = (short)f2h(src[j]);
      *(short8v*)(W2h + (size_t)id2 * 8) = H;
    }
  } else if (bid < 1680) {                         // W3: R=2048, K=512
    int id = (bid - 1168) * 256 + threadIdx.x;
    int l = id & 63, mb = (id >> 6) & 127, kt = id >> 13;
    int n = mb * 16 + (l & 15);
    int k0 = kt * 32 + ((l >> 4) << 3);
    int g = n >> 5, kk = n & 31;
    short8v H;
    if (kk < 29) {
      const float* src = W3 + ((size_t)((g + 64) * 29 + kk)) * HID + k0;
#pragma unroll
      for (int j = 0; j < 8; ++j) H[j] = (short)f2h(src[j]);
    } else {
#pragma unroll
      for (int j = 0; j < 8; ++j) H[j] = 0;
    }
    *(short8v*)(W3h + (size_t)id * 8) = H;
  } else {                                         // b3p: 2048
    int n = (bid - 1680) * 256 + threadIdx.x;
    int g = n >> 5, kk = n & 31;
    b3p[n] = (kk < 29) ? b3[(g + 64) * 29 + kk] : 0.f;
  }
}

// ------------- v14 mainloop: BM=BN=128, BK=64 phases, 4 waves (2x2) -------------

__device__ __forceinline__ void stageA_v14(const u16* __restrict__ A, size_t ab, u16* Lb, int t) {
  async16(A + ab + t * 8,         Lb + t * 8);
  async16(A + ab + (t + 256) * 8, Lb + (t + 256) * 8);
}

template<int NKT>
__device__ __forceinline__ void gemm_mainloop_v14(
    const u16* __restrict__ A, const u16* __restrict__ B,
    int a_mb0, int a_rs16, int b_nb0, int b_rs16,
    u16* LDS, f32x4 acc[4][4]) {
  constexpr int NPH = NKT / 2;
  const int t = threadIdx.x;
  const int lane = t & 63;
  const int wv = t >> 6;
  const int wr = wv >> 1, wc = wv & 1;
  const size_t aStep = (size_t)a_rs16 * 512;       // u16 per K-tile
  const size_t bStep = (size_t)b_rs16 * 512;
  const size_t ab0 = (size_t)a_mb0 * 512;
  const u16* Bp = B + (((size_t)(b_nb0 + wc * 4)) * 64 + lane) * 8;

  half8 b[2][4];
#pragma unroll
  for (int nf = 0; nf < 4; ++nf) b[0][nf] = *(const half8*)(Bp + nf * 512);
  // prologue: stage pair 0 (kt 0,1) into pair-buffer 0
  stageA_v14(A, ab0, LDS, t);
  stageA_v14(A, ab0 + aStep, LDS + 4096, t);

#pragma unroll
  for (int p = 0; p < NPH; ++p) {
    if (p + 1 < NPH) {
      u16* pb = LDS + ((p + 1) % 3) * 8192;
      stageA_v14(A, ab0 + (size_t)(2 * p + 2) * aStep, pb, t);
      stageA_v14(A, ab0 + (size_t)(2 * p + 3) * aStep, pb + 4096, t);
      vwait(4);          // pair p retired (A-only counting; B-loads only add conservatism)
    } else {
      vwait(0);
    }
    __builtin_amdgcn_s_barrier();                  // all waves see pair p in LDS
    __builtin_amdgcn_sched_barrier(0);             // pin ds_reads after barrier
    const u16* cb = LDS + (p % 3) * 8192;
#pragma unroll
    for (int ktl = 0; ktl < 2; ++ktl) {
      const int kt = 2 * p + ktl;
      if (kt + 1 < NKT) {
#pragma unroll
        for (int nf = 0; nf < 4; ++nf)
          b[(kt + 1) & 1][nf] = *(const half8*)(Bp + (size_t)(kt + 1) * bStep + nf * 512);
      }
      half8 a[4];
#pragma unroll
      for (int mf = 0; mf < 4; ++mf)
        a[mf] = *(const half8*)(cb + ktl * 4096 + ((wr * 4 + mf) * 64 + lane) * 8);
#pragma unroll
      for (int mf = 0; mf < 4; ++mf)
#pragma unroll
        for (int nf = 0; nf < 4; ++nf)
          acc[mf][nf] = __builtin_amdgcn_mfma_f32_16x16x32_f16(a[mf], b[kt & 1][nf], acc[mf][nf], 0, 0, 0);
    }
  }
}

// ---------------- GEMM + bias + relu -> f16 (FL output, R=BATCH) ----------------

template<int NKT>
__global__ __launch_bounds__(256, 3) void gemm_relu_v14(
    const u16* __restrict__ A, const u16* __restrict__ B,
    const float* __restrict__ bias, u16* __restrict__ C, int a_rs16) {
  __shared__ __align__(16) u16 LDS[24576];        // 48 KB: 3 pair-buffers x 16 KB
  const int bid = xcd_swz(blockIdx.x, gridDim.x);
  const int nt = bid & 3;                         // N = 512
  const int mt = bid >> 2;
  const int m0 = mt << 7, n0 = nt << 7;
  f32x4 zero = {0.f, 0.f, 0.f, 0.f};
  f32x4 acc[4][4];
#pragma unroll
  for (int i = 0; i < 4; ++i)
#pragma unroll
    for (int j = 0; j < 4; ++j) acc[i][j] = zero;

  gemm_mainloop_v14<NKT>(A, B, m0 >> 4, a_rs16, n0 >> 4, 32, LDS, acc);

  const int lane = threadIdx.x & 63;
  const int wv = threadIdx.x >> 6;
  const int wr = wv >> 1, wc = wv & 1;
#pragma unroll
  for (int mf = 0; mf < 4; ++mf) {
#pragma unroll
    for (int nf = 0; nf < 4; ++nf) {
      int col = n0 + wc * 64 + nf * 16 + (lane & 15);
      float bv = bias[col];
#pragma unroll
      for (int r = 0; r < 4; ++r) {
        int row = m0 + wr * 64 + mf * 16 + (lane >> 4) * 4 + r;
        float v = fmaxf(acc[mf][nf][r] + bv, 0.f);
        // FL store (R=BATCH, rs16=2048)
        int ktO = col >> 5, mbO = row >> 4;
        int lO = (row & 15) | (((col >> 3) & 3) << 4);
        int jO = col & 7;
        size_t off = (((size_t)ktO * (BATCH >> 4) + mbO) * 64 + lO) * 8 + jO;
        C[off] = f2h(v);
      }
    }
  }
}

// ---------------- RQS spline (per (row, dim)) ----------------

__device__ __forceinline__ void rqs(float xin, const float uw[10], const float uh[10], const float ud9[9],
                                    float& yv, float& ldv) {
  float mw = uw[0];
#pragma unroll
  for (int i = 1; i < 10; ++i) mw = fmaxf(mw, uw[i]);
  float ew[10]; float sw = 0.f;
#pragma unroll
  for (int i = 0; i < 10; ++i) { ew[i] = __expf(uw[i] - mw); sw += ew[i]; }
  float invw = 0.99f / sw;
  float cw[11]; cw[0] = -5.f;
  {
    float run = 0.f;
#pragma unroll
    for (int i = 0; i < 10; ++i) { run += 0.001f + invw * ew[i]; cw[i + 1] = 10.f * run - 5.f; }
  }
  cw[10] = 5.f;
  float mh = uh[0];
#pragma unroll
  for (int i = 1; i < 10; ++i) mh = fmaxf(mh, uh[i]);
  float eh[10]; float sh = 0.f;
#pragma unroll
  for (int i = 0; i < 10; ++i) { eh[i] = __expf(uh[i] - mh); sh += eh[i]; }
  float invh = 0.99f / sh;
  float ch[11]; ch[0] = -5.f;
  {
    float run = 0.f;
#pragma unroll
    for (int i = 0; i < 10; ++i) { run += 0.001f + invh * eh[i]; ch[i + 1] = 10.f * run - 5.f; }
  }
  ch[10] = 5.f;
  float dv[11]; dv[0] = 1.f; dv[10] = 1.f;
#pragma unroll
  for (int i = 0; i < 9; ++i) {
    float x = ud9[i];
    float sp = fmaxf(x, 0.f) + __logf(1.f + __expf(-fabsf(x)));
    dv[i + 1] = 0.001f + sp;
  }

  float xc = fminf(fmaxf(xin, -5.f), 5.f);
  int b = 0;
#pragma unroll
  for (int j = 1; j <= 10; ++j) b += (cw[j] <= xc) ? 1 : 0;
  b = (b > 9) ? 9 : b;

  float wk = cw[1] - cw[0], cwk = cw[0], hk = ch[1] - ch[0], chk = ch[0], dk = dv[0], dk1 = dv[1];
#pragma unroll
  for (int j = 1; j < 10; ++j) {
    if (j == b) { wk = cw[j + 1] - cw[j]; cwk = cw[j]; hk = ch[j + 1] - ch[j]; chk = ch[j]; dk = dv[j]; dk1 = dv[j + 1]; }
  }

  float th = (xc - cwk) / wk;
  float sr = hk / wk;
  float omth = 1.f - th;
  float tm = th * omth;
  float den = sr + (dk + dk1 - 2.f * sr) * tm;
  float num = hk * (sr * th * th + dk * tm);
  float y = chk + num / den;
  float ld = __logf(sr * sr * (dk1 * th * th + 2.f * sr * tm + dk * omth * omth)) - 2.f * __logf(den);
  bool inside = (xin >= -5.f) && (xin <= 5.f);
  yv = inside ? y : xin;
  ldv = inside ? ld : 0.f;
  if (!isfinite(yv)) yv = 0.f;
}

// ---------------- GEMM3 fused with spline epilogue ----------------
// PT: row stride 132 f32 (== 4 mod 32), dim-group stride 33 => 2-way max (free).

__global__ __launch_bounds__(256, 3) void gemm3_spline_v14(
    const u16* __restrict__ A, const u16* __restrict__ B,
    const float* __restrict__ b3p, const float* __restrict__ z,
    float* __restrict__ xout, float* __restrict__ partial) {
  __shared__ __align__(16) char SMEM[49152];      // 3 pair-buffers x 16 KB, aliased with PT
  u16* LDS = (u16*)SMEM;
  float* PTf = (float*)SMEM;                      // [64][132] = 33792 B
  const int bid = xcd_swz(blockIdx.x, gridDim.x);
  const int nt = bid & 15;
  const int mt = bid >> 4;
  const int m0 = mt << 7, n0 = nt << 7;
  f32x4 zero = {0.f, 0.f, 0.f, 0.f};
  f32x4 acc[4][4];
#pragma unroll
  for (int i = 0; i < 4; ++i)
#pragma unroll
    for (int j = 0; j < 4; ++j) acc[i][j] = zero;

  gemm_mainloop_v14<16>(A, B, m0 >> 4, BATCH >> 4, n0 >> 4, NPAD >> 4, LDS, acc);

  const int t = threadIdx.x;
  const int lane = t & 63;
  const int wv = t >> 6;
  const int wr = wv >> 1, wc = wv & 1;
  const int gb = n0 >> 5;   // global transformed-dim base for this block (4 dims)

  for (int p = 0; p < 2; ++p) {
    __syncthreads();
    if (wr == p) {
#pragma unroll
      for (int mf = 0; mf < 4; ++mf)
#pragma unroll
        for (int nf = 0; nf < 4; ++nf)
#pragma unroll
          for (int r = 0; r < 4; ++r) {
            int cl = wc * 64 + nf * 16 + (lane & 15);         // local col 0..127
            int rowl = mf * 16 + (lane >> 4) * 4 + r;         // 0..63
            PTf[rowl * 132 + (cl >> 5) * 33 + (cl & 31)] = acc[mf][nf][r];
          }
    }
    __syncthreads();

    const int rl = t >> 2;          // 0..63
    const int g = t & 3;            // local dim 0..3
    const int row = p * 64 + rl;
    const int grow = m0 + row;
    const float* pr = PTf + rl * 132 + g * 33;
    const float* bb = b3p + n0 + g * 32;
    float uw[10], uh[10], ud9[9];
#pragma unroll
    for (int i = 0; i < 10; ++i) uw[i] = pr[i] + bb[i];
#pragma unroll
    for (int i = 0; i < 10; ++i) uh[i] = pr[10 + i] + bb[10 + i];
#pragma unroll
    for (int i = 0; i < 9; ++i) ud9[i] = pr[20 + i] + bb[20 + i];

    float xin = z[(long)grow * DIM + 64 + gb + g];
    float yv, ldv;
    rqs(xin, uw, uh, ud9, yv, ldv);

    xout[(long)grow * DIM + 64 + gb + g] = yv;

    float s = ldv;
    s += __shfl_down(s, 1);
    s += __shfl_down(s, 2);
    if (g == 0) partial[(long)nt * BATCH + grow] = s;
  }
}

// ---------------- pass-through copy + logdet reduce ----------------

__global__ __launch_bounds__(256) void copy_first_v14(const float* __restrict__ z, float* __restrict__ xout) {
  int id = blockIdx.x * 256 + threadIdx.x;        // < 32768*16
  int m = id >> 4, c4 = id & 15;
  const float4 v = *(const float4*)(z + (long)m * DIM + c4 * 4);
  *(float4*)(xout + (long)m * DIM + c4 * 4) = v;
}

__global__ __launch_bounds__(256) void reduce_ld_v14(const float* __restrict__ partial, float* __restrict__ ldout) {
  int row = blockIdx.x * 256 + threadIdx.x;
  float s = 0.f;
#pragma unroll
  for (int i = 0; i < 16; ++i) s += partial[(long)i * BATCH + row];
  if (!isfinite(s)) s = 0.f;
  ldout[row] = s;
}

// ---------------- launch ----------------

extern "C" void kernel_launch(void* const* d_in, const int* in_sizes, int n_in,
                              void* d_out, int out_size, void* d_ws, size_t ws_size,
                              hipStream_t stream) {
  const float* z  = (const float*)d_in[0];
  const float* W1 = (const float*)d_in[1];
  const float* b1 = (const float*)d_in[2];
  const float* W2 = (const float*)d_in[3];
  const float* b2 = (const float*)d_in[4];
  const float* W3 = (const float*)d_in[5];
  const float* b3 = (const float*)d_in[6];
  float* xout  = (float*)d_out;
  float* ldout = xout + (size_t)BATCH * DIM;

  char* ws = (char*)d_ws;
  u16* W1h = (u16*)ws;  ws += (size_t)512 * 64 * 2;
  u16* W2h = (u16*)ws;  ws += (size_t)512 * 512 * 2;
  u16* W3h = (u16*)ws;  ws += (size_t)NPAD * HID * 2;
  float* b3p = (float*)ws; ws += (size_t)NPAD * 4;
  // za and part alias (disjoint lifetimes: za consumed by gemm1; part written by gemm3)
  u16* zah  = (u16*)ws;
  float* part = (float*)ws; ws += (size_t)BATCH * 64 * 2;   // 4 MB (part needs 2 MB)
  u16* h1h = (u16*)ws;  ws += (size_t)BATCH * HID * 2;
  u16* h2h = (u16*)ws;  ws += (size_t)BATCH * HID * 2;

  prep_all_v14<<<1688, 256, 0, stream>>>(z, W1, W2, W3, b3, zah, W1h, W2h, W3h, b3p);

  // GEMM1: A = za (R=BATCH, rs16=2048), K=64 (NKT=2, 1 phase)
  gemm_relu_v14<2><<<(BATCH / 128) * 4, 256, 0, stream>>>(zah, W1h, b1, h1h, BATCH >> 4);
  // GEMM2: A = h1 (R=BATCH), K=512 (NKT=16, 8 phases)
  gemm_relu_v14<16><<<(BATCH / 128) * 4, 256, 0, stream>>>(h1h, W2h, b2, h2h, BATCH >> 4);
  // GEMM3 + spline
  gemm3_spline_v14<<<(BATCH / 128) * (NPAD / 128), 256, 0, stream>>>(h2h, W3h, b3p, z, xout, part);

  copy_first_v14<<<(BATCH * 16) / 256, 256, 0, stream>>>(z, xout);
  reduce_ld_v14<<<BATCH / 256, 256, 0, stream>>>(part, ldout);
}